// Round 12
// baseline (109.826 us; speedup 1.0000x reference)
//
#include <hip/hip_runtime.h>
#include <math.h>

// Problem constants (fixed-shape problem)
#define NPTS 8192
#define CCH  128
#define KNN  16
#define BN_RS 0.9999950000374997f   // 1/sqrt(1 + 1e-5)

typedef unsigned long long u64;
typedef unsigned short u16;

__device__ __forceinline__ u16 f2bf(float f) {   // round-to-nearest-even
    unsigned u = __float_as_uint(f);
    u += 0x7FFFu + ((u >> 16) & 1u);
    return (u16)(u >> 16);
}

__device__ __forceinline__ void bf8_to_f(const uint4 u, float* f) {
    f[0] = __uint_as_float(u.x << 16); f[1] = __uint_as_float(u.x & 0xffff0000u);
    f[2] = __uint_as_float(u.y << 16); f[3] = __uint_as_float(u.y & 0xffff0000u);
    f[4] = __uint_as_float(u.z << 16); f[5] = __uint_as_float(u.z & 0xffff0000u);
    f[6] = __uint_as_float(u.w << 16); f[7] = __uint_as_float(u.w & 0xffff0000u);
}

// ---------------------------------------------------------------------------
// Kernel P: pack candidate points as float4 (x, y, z, |p|^2)
// ---------------------------------------------------------------------------
__global__ __launch_bounds__(256) void pack_kernel(const float* __restrict__ p,
                                                   float4* __restrict__ c4) {
    const int j = blockIdx.x * 256 + threadIdx.x;
    if (j < NPTS) {
        const float x = p[3 * j + 0], y = p[3 * j + 1], z = p[3 * j + 2];
        c4[j] = make_float4(x, y, z, x * x + y * y + z * z);
    }
}

// ---------------------------------------------------------------------------
// Kernel A: KNN via sampled-threshold 1.25-pass select.
// R12 change: phase A now reads candidates from block-shared LDS tiles
// (was: every wave streamed 64 KB from L2 -> 256 MB total; now staged once
// per block -> 64 MB).  Candidate->lane partition identical, so tau is
// bit-identical to R9/R11.
// ---------------------------------------------------------------------------
#define QW    2
#define CAP   104
#define TILE  1024
#define SAMPN 4096

__device__ __forceinline__ u64 bitonic64(u64 v, const int lane) {
    #pragma unroll
    for (int k = 2; k <= 64; k <<= 1) {
        #pragma unroll
        for (int j = k >> 1; j > 0; j >>= 1) {
            const u64  o       = __shfl_xor(v, j);
            const bool takemin = (((lane & j) == 0) == ((lane & k) == 0));
            v = ((o < v) == takemin) ? o : v;
        }
    }
    return v;
}

__device__ __forceinline__ float bitonicf(float v, const int lane) {
    #pragma unroll
    for (int k = 2; k <= 64; k <<= 1) {
        #pragma unroll
        for (int j = k >> 1; j > 0; j >>= 1) {
            const float o      = __shfl_xor(v, j);
            const bool takemin = (((lane & j) == 0) == ((lane & k) == 0));
            v = ((o < v) == takemin) ? o : v;
        }
    }
    return v;
}

__device__ __forceinline__ float make_d2(const float4 c, const float m2x, const float m2y,
                                         const float m2z, const float qb) {
    float d2 = fmaf(m2x, c.x, fmaf(m2y, c.y, fmaf(m2z, c.z, c.w + qb)));
    return fmaxf(d2, 0.0f);
}

__global__ __launch_bounds__(256) void knn_kernel(const float4* __restrict__ c4,
                                                  int* __restrict__ oidx,
                                                  float* __restrict__ od2) {
    __shared__ float4 s_pt[TILE];            // 16 KB
    __shared__ u64    s_col[4][QW][CAP];     // 6.5 KB
    __shared__ int    s_cnt[4][QW];

    const int t     = threadIdx.x;
    const int wave  = t >> 6;
    const int lane  = t & 63;
    const int qbase = (blockIdx.x * 4 + wave) * QW;

    float m2x[QW], m2y[QW], m2z[QW], qb[QW];
    #pragma unroll
    for (int qi = 0; qi < QW; ++qi) {
        const float4 q = c4[qbase + qi];
        m2x[qi] = -2.0f * q.x;
        m2y[qi] = -2.0f * q.y;
        m2z[qi] = -2.0f * q.z;
        qb[qi]  = q.w;
    }
    if (lane < QW) s_cnt[wave][lane] = 0;   // synced by first staging barrier

    // ---- phase A: lane minima over first SAMPN candidates, LDS-tiled ----
    float bd[QW];
    #pragma unroll
    for (int qi = 0; qi < QW; ++qi) bd[qi] = 3.0e38f;

    for (int tb = 0; tb < SAMPN; tb += TILE) {
        __syncthreads();
        for (int jj = t; jj < TILE; jj += 256) s_pt[jj] = c4[tb + jj];
        __syncthreads();
        for (int l = lane; l < TILE; l += 128) {
            const float4 c0 = s_pt[l];
            const float4 c1 = s_pt[l + 64];
            #pragma unroll
            for (int qi = 0; qi < QW; ++qi) {
                const float d0 = make_d2(c0, m2x[qi], m2y[qi], m2z[qi], qb[qi]);
                const float d1 = make_d2(c1, m2x[qi], m2y[qi], m2z[qi], qb[qi]);
                bd[qi] = fminf(bd[qi], fminf(d0, d1));
            }
        }
    }

    float tauf[QW];
    #pragma unroll
    for (int qi = 0; qi < QW; ++qi) {
        const float s = bitonicf(bd[qi], lane);
        tauf[qi] = __shfl(s, 15);
    }

    // ---- phase B: collect pass over LDS tiles ----
    for (int tb = 0; tb < NPTS; tb += TILE) {
        __syncthreads();
        for (int jj = t; jj < TILE; jj += 256) s_pt[jj] = c4[tb + jj];
        __syncthreads();
        for (int l = lane; l < TILE; l += 128) {
            const float4 c0 = s_pt[l];
            const float4 c1 = s_pt[l + 64];
            const int j0 = tb + l, j1 = tb + l + 64;
            #pragma unroll
            for (int qi = 0; qi < QW; ++qi) {
                const float d0 = make_d2(c0, m2x[qi], m2y[qi], m2z[qi], qb[qi]);
                const float d1 = make_d2(c1, m2x[qi], m2y[qi], m2z[qi], qb[qi]);
                if (d0 <= tauf[qi]) {
                    const int pos = atomicAdd(&s_cnt[wave][qi], 1);
                    if (pos < CAP)
                        s_col[wave][qi][pos] = ((u64)__float_as_uint(d0) << 32) | (u64)(unsigned)j0;
                }
                if (d1 <= tauf[qi]) {
                    const int pos = atomicAdd(&s_cnt[wave][qi], 1);
                    if (pos < CAP)
                        s_col[wave][qi][pos] = ((u64)__float_as_uint(d1) << 32) | (u64)(unsigned)j1;
                }
            }
        }
    }

    // ---- final select per query ----
    #pragma unroll 1
    for (int qi = 0; qi < QW; ++qi) {
        const int q = qbase + qi;
        int M = s_cnt[wave][qi];

        if (M > CAP) {
            float fb = 3.0e38f;
            for (int l = lane; l < NPTS; l += 64)
                fb = fminf(fb, make_d2(c4[l], m2x[qi], m2y[qi], m2z[qi], qb[qi]));
            const float s    = bitonicf(fb, lane);
            const float tau2 = __shfl(s, 15);
            if (lane == 0) s_cnt[wave][qi] = 0;
            for (int l = lane; l < NPTS; l += 64) {
                const float d = make_d2(c4[l], m2x[qi], m2y[qi], m2z[qi], qb[qi]);
                if (d <= tau2) {
                    const int pos = atomicAdd(&s_cnt[wave][qi], 1);
                    if (pos < CAP)
                        s_col[wave][qi][pos] = ((u64)__float_as_uint(d) << 32) | (u64)(unsigned)l;
                }
            }
            M = s_cnt[wave][qi];
            if (M > CAP) M = CAP;
        }

        if (M <= 64) {
            u64 v = (lane < M) ? s_col[wave][qi][lane] : ~0ull;
            v = bitonic64(v, lane);
            if (lane < KNN) {
                oidx[q * KNN + lane] = (int)(v & 0xffffffffu);
                od2 [q * KNN + lane] = __uint_as_float((unsigned)(v >> 32));
            }
        } else {
            u64 a = (lane < M) ? s_col[wave][qi][lane] : ~0ull;
            a = bitonic64(a, lane);
            u64 b = (lane + 64 < M) ? s_col[wave][qi][lane + 64] : ~0ull;
            b = bitonic64(b, lane);
            const u64 bs = __shfl(b, lane & 15);
            u64 mv = (lane < 16) ? a : ((lane < 32) ? bs : ~0ull);
            mv = bitonic64(mv, lane);
            if (lane < KNN) {
                oidx[q * KNN + lane] = (int)(mv & 0xffffffffu);
                od2 [q * KNN + lane] = __uint_as_float((unsigned)(mv >> 32));
            }
        }
    }
}

// ---------------------------------------------------------------------------
// Kernel B: three fp32 GEMMs; xq fp32, xk/xv bf16 (R11 version, verbatim).
// ---------------------------------------------------------------------------
__global__ __launch_bounds__(256) void gemm3_kernel(
    const float* __restrict__ x,
    const float* __restrict__ Wq, const float* __restrict__ bq,
    const float* __restrict__ Wk, const float* __restrict__ bk,
    const float* __restrict__ Wv, const float* __restrict__ bv,
    float* __restrict__ xq, u16* __restrict__ xk16, u16* __restrict__ xv16) {
    const int which = blockIdx.z;
    const float* W    = (which == 0) ? Wq : (which == 1) ? Wk : Wv;
    const float* bias = (which == 0) ? bq : (which == 1) ? bk : bv;

    const int row0 = blockIdx.x * 64;
    const int col0 = blockIdx.y * 64;

    __shared__ float As[64][68];
    __shared__ float Bs[64][68];

    const int t  = threadIdx.x;
    const int lr = t >> 4;
    const int lc = t & 15;
    const int or0 = (t >> 4) * 4;
    const int oc0 = (t & 15) * 4;

    float acc[4][4] = {};

    for (int kk = 0; kk < CCH; kk += 64) {
        __syncthreads();
        #pragma unroll
        for (int i = 0; i < 4; ++i) {
            const int r = lr + i * 16;
            *(float4*)&As[r][lc * 4] =
                *(const float4*)&x[(size_t)(row0 + r) * CCH + kk + lc * 4];
            *(float4*)&Bs[r][lc * 4] =
                *(const float4*)&W[(size_t)(kk + r) * CCH + col0 + lc * 4];
        }
        __syncthreads();
        #pragma unroll 8
        for (int k = 0; k < 64; ++k) {
            const float a0 = As[or0 + 0][k];
            const float a1 = As[or0 + 1][k];
            const float a2 = As[or0 + 2][k];
            const float a3 = As[or0 + 3][k];
            const float4 b = *(const float4*)&Bs[k][oc0];
            acc[0][0] += a0 * b.x; acc[0][1] += a0 * b.y; acc[0][2] += a0 * b.z; acc[0][3] += a0 * b.w;
            acc[1][0] += a1 * b.x; acc[1][1] += a1 * b.y; acc[1][2] += a1 * b.z; acc[1][3] += a1 * b.w;
            acc[2][0] += a2 * b.x; acc[2][1] += a2 * b.y; acc[2][2] += a2 * b.z; acc[2][3] += a2 * b.w;
            acc[3][0] += a3 * b.x; acc[3][1] += a3 * b.y; acc[3][2] += a3 * b.z; acc[3][3] += a3 * b.w;
        }
    }

    const float4 bb = *(const float4*)&bias[col0 + oc0];
    if (which == 0) {
        #pragma unroll
        for (int i = 0; i < 4; ++i) {
            const int r = row0 + or0 + i;
            float4 o;
            o.x = acc[i][0] + bb.x;
            o.y = acc[i][1] + bb.y;
            o.z = acc[i][2] + bb.z;
            o.w = acc[i][3] + bb.w;
            *(float4*)&xq[(size_t)r * CCH + col0 + oc0] = o;
        }
    } else {
        u16* o16 = (which == 1) ? xk16 : xv16;
        #pragma unroll
        for (int i = 0; i < 4; ++i) {
            const int r = row0 + or0 + i;
            ushort4 h;
            h.x = f2bf(acc[i][0] + bb.x);
            h.y = f2bf(acc[i][1] + bb.y);
            h.z = f2bf(acc[i][2] + bb.z);
            h.w = f2bf(acc[i][3] + bb.w);
            *(ushort4*)&o16[(size_t)r * CCH + col0 + oc0] = h;
        }
    }
}

// ---------------------------------------------------------------------------
// Kernel C: fused per-point attention, v8 = v7 + PPB=2.
// Amortizes per-block overheads 2x (w1t staging, ww2row, scalars) and issues
// both points' gathers up front.  Hazards: s_val parity double-buffered
// (phase-4(j0) reads s_val[0] while phase-1(j1) writes s_val[1]); s_w2 write
// (j1) is after B0(j1) > B2(j0) > softmax-read(j0); s_wn write (j1) is after
// B1(j1) > phase-4 read (j0).  Barriers: 3 per point, unchanged.
// LDS 27.9 KB -> 5 blocks/CU (20 waves, same 62% cap as measured in v7).
// ---------------------------------------------------------------------------
#define PPB 2

__global__ __launch_bounds__(256) void fused_kernel(
    const float* __restrict__ p,
    const float* __restrict__ xqg, const u16* __restrict__ xkg, const u16* __restrict__ xvg,
    const int* __restrict__ nidx, const float* __restrict__ nd2,
    const float* __restrict__ Wp1, const float* __restrict__ bp1,
    const float* __restrict__ g1,  const float* __restrict__ be1,
    const float* __restrict__ Wp2, const float* __restrict__ bp2,
    const float* __restrict__ g2,  const float* __restrict__ be2,
    const float* __restrict__ Ww1, const float* __restrict__ bw1,
    const float* __restrict__ g3,  const float* __restrict__ be3,
    const float* __restrict__ Ww2, const float* __restrict__ bw2,
    float* __restrict__ out) {
    const int i0 = blockIdx.x * PPB;
    const int t  = threadIdx.x;

    __shared__ float s_w1tA[16][66];
    __shared__ float s_w1tB[16][66];
    __shared__ float s_val[PPB][16][132];
    __shared__ float s_w2[16][17];
    __shared__ float s_wn[16][17];

    const int k  = t >> 4;
    const int tl = t & 15;
    const int c0 = tl * 8;

    // ---- neighbor meta + gathers for BOTH points, issued up front ----
    const int   jn0 = nidx[(i0 + 0) * KNN + k];
    const int   jn1 = nidx[(i0 + 1) * KNN + k];
    const float d20 = nd2[(i0 + 0) * KNN + k];
    const float d21 = nd2[(i0 + 1) * KNN + k];
    const uint4 ku0 = *(const uint4*)&xkg[(size_t)jn0 * CCH + c0];
    const uint4 vu0 = *(const uint4*)&xvg[(size_t)jn0 * CCH + c0];
    const uint4 ku1 = *(const uint4*)&xkg[(size_t)jn1 * CCH + c0];
    const uint4 vu1 = *(const uint4*)&xvg[(size_t)jn1 * CCH + c0];

    // ---- once-per-block hoists ----
    float ww2row[16];
    {
        const float4 r0 = *(const float4*)&Ww2[tl * 16 + 0];
        const float4 r1 = *(const float4*)&Ww2[tl * 16 + 4];
        const float4 r2 = *(const float4*)&Ww2[tl * 16 + 8];
        const float4 r3 = *(const float4*)&Ww2[tl * 16 + 12];
        ww2row[0]=r0.x; ww2row[1]=r0.y; ww2row[2]=r0.z; ww2row[3]=r0.w;
        ww2row[4]=r1.x; ww2row[5]=r1.y; ww2row[6]=r1.z; ww2row[7]=r1.w;
        ww2row[8]=r2.x; ww2row[9]=r2.y; ww2row[10]=r2.z; ww2row[11]=r2.w;
        ww2row[12]=r3.x; ww2row[13]=r3.y; ww2row[14]=r3.z; ww2row[15]=r3.w;
    }
    const float bw1m = bw1[tl];
    const float g3m  = g3[tl] * BN_RS;
    const float be3m = be3[tl];
    const float bw2m = bw2[tl];

    // ---- stage Ww1 transposed/split/padded (once per block) ----
    #pragma unroll
    for (int j = 0; j < 8; ++j) {
        const int e2   = t + j * 256;
        const int m    = e2 & 15;
        const int csrc = e2 >> 4;
        const int col  = ((csrc >> 3) << 2) | (csrc & 3);
        const float v  = Ww1[e2];
        if (csrc & 4) s_w1tB[m][col] = v;
        else          s_w1tA[m][col] = v;
    }

    #pragma unroll
    for (int j = 0; j < PPB; ++j) {
        const int   i   = i0 + j;
        const int   jn  = j ? jn1 : jn0;
        const float d2v = j ? d21 : d20;
        const uint4 ku  = j ? ku1 : ku0;
        const uint4 vu  = j ? vu1 : vu0;

        // ---- phase 1: pr + wv (regs) + val (LDS, parity buffer) ----
        const float dw  = __expf(-sqrtf(fmaxf(d2v, 0.f)));
        const float prx = p[jn * 3 + 0] - p[i * 3 + 0];
        const float pry = p[jn * 3 + 1] - p[i * 3 + 1];
        const float prz = p[jn * 3 + 2] - p[i * 3 + 2];
        float tt[3];
        #pragma unroll
        for (int e = 0; e < 3; ++e) {
            float v = prx * Wp1[0 * 3 + e] + pry * Wp1[1 * 3 + e] + prz * Wp1[2 * 3 + e] + bp1[e];
            v = v * (g1[e] * BN_RS) + be1[e];
            tt[e] = fmaxf(v, 0.f);
        }

        float xk8[8], xv8[8];
        bf8_to_f(ku, xk8);
        bf8_to_f(vu, xv8);

        float wv8[8];
        #pragma unroll
        for (int h = 0; h < 2; ++h) {
            const int cc = c0 + h * 4;
            const float4 w0  = *(const float4*)&Wp2[cc];
            const float4 w1  = *(const float4*)&Wp2[128 + cc];
            const float4 w2  = *(const float4*)&Wp2[256 + cc];
            const float4 bp  = *(const float4*)&bp2[cc];
            const float4 xq4 = *(const float4*)&xqg[(size_t)i * CCH + cc];
            const float4 gg  = *(const float4*)&g2[cc];
            const float4 bb  = *(const float4*)&be2[cc];
            float4 val4;
            {
                const float pr = tt[0] * w0.x + tt[1] * w1.x + tt[2] * w2.x + bp.x;
                wv8[h * 4 + 0] = fmaxf(((xq4.x - xk8[h * 4 + 0]) + pr) * (gg.x * BN_RS) + bb.x, 0.f);
                val4.x = xv8[h * 4 + 0] * dw + pr;
            }
            {
                const float pr = tt[0] * w0.y + tt[1] * w1.y + tt[2] * w2.y + bp.y;
                wv8[h * 4 + 1] = fmaxf(((xq4.y - xk8[h * 4 + 1]) + pr) * (gg.y * BN_RS) + bb.y, 0.f);
                val4.y = xv8[h * 4 + 1] * dw + pr;
            }
            {
                const float pr = tt[0] * w0.z + tt[1] * w1.z + tt[2] * w2.z + bp.z;
                wv8[h * 4 + 2] = fmaxf(((xq4.z - xk8[h * 4 + 2]) + pr) * (gg.z * BN_RS) + bb.z, 0.f);
                val4.z = xv8[h * 4 + 2] * dw + pr;
            }
            {
                const float pr = tt[0] * w0.w + tt[1] * w1.w + tt[2] * w2.w + bp.w;
                wv8[h * 4 + 3] = fmaxf(((xq4.w - xk8[h * 4 + 3]) + pr) * (gg.w * BN_RS) + bb.w, 0.f);
                val4.w = xv8[h * 4 + 3] * dw + pr;
            }
            *(float4*)&s_val[j][k][cc] = val4;
        }
        __syncthreads();                                   // B0

        // ---- phase 2: all-m partials + butterfly #1 ----
        float pp[16];
        #pragma unroll
        for (int m = 0; m < 16; ++m) {
            const float4 a = *(const float4*)&s_w1tA[m][tl * 4];
            const float4 b = *(const float4*)&s_w1tB[m][tl * 4];
            pp[m] = wv8[0] * a.x + wv8[1] * a.y + wv8[2] * a.z + wv8[3] * a.w
                  + wv8[4] * b.x + wv8[5] * b.y + wv8[6] * b.z + wv8[7] * b.w;
        }
        {
            float q8[8];
            #pragma unroll
            for (int jj = 0; jj < 8; ++jj) {
                const float send = (tl & 8) ? pp[jj] : pp[jj + 8];
                const float keep = (tl & 8) ? pp[jj + 8] : pp[jj];
                q8[jj] = keep + __shfl_xor(send, 8);
            }
            float q4[4];
            #pragma unroll
            for (int jj = 0; jj < 4; ++jj) {
                const float send = (tl & 4) ? q8[jj] : q8[jj + 4];
                const float keep = (tl & 4) ? q8[jj + 4] : q8[jj];
                q4[jj] = keep + __shfl_xor(send, 4);
            }
            float q2[2];
            #pragma unroll
            for (int jj = 0; jj < 2; ++jj) {
                const float send = (tl & 2) ? q4[jj] : q4[jj + 2];
                const float keep = (tl & 2) ? q4[jj + 2] : q4[jj];
                q2[jj] = keep + __shfl_xor(send, 2);
            }
            const float s1 = (tl & 1) ? q2[0] : q2[1];
            const float k1 = (tl & 1) ? q2[1] : q2[0];
            pp[0] = k1 + __shfl_xor(s1, 1);        // w1[k][m=tl]
        }

        const float rr = fmaxf((pp[0] + bw1m) * g3m + be3m, 0.f);

        // ---- butterfly #2: w2[k][m2] ----
        float p2[16];
        #pragma unroll
        for (int j2 = 0; j2 < 16; ++j2) p2[j2] = rr * ww2row[j2];
        float w2v;
        {
            float q8[8];
            #pragma unroll
            for (int jj = 0; jj < 8; ++jj) {
                const float send = (tl & 8) ? p2[jj] : p2[jj + 8];
                const float keep = (tl & 8) ? p2[jj + 8] : p2[jj];
                q8[jj] = keep + __shfl_xor(send, 8);
            }
            float q4[4];
            #pragma unroll
            for (int jj = 0; jj < 4; ++jj) {
                const float send = (tl & 4) ? q8[jj] : q8[jj + 4];
                const float keep = (tl & 4) ? q8[jj + 4] : q8[jj];
                q4[jj] = keep + __shfl_xor(send, 4);
            }
            float q2[2];
            #pragma unroll
            for (int jj = 0; jj < 2; ++jj) {
                const float send = (tl & 2) ? q4[jj] : q4[jj + 2];
                const float keep = (tl & 2) ? q4[jj + 2] : q4[jj];
                q2[jj] = keep + __shfl_xor(send, 2);
            }
            const float s1 = (tl & 1) ? q2[0] : q2[1];
            const float k1 = (tl & 1) ? q2[1] : q2[0];
            w2v = k1 + __shfl_xor(s1, 1) + bw2m;   // w2[k][m2=tl]
        }
        s_w2[k][tl] = w2v;
        __syncthreads();                                   // B1

        // ---- phase 3: softmax over k (per-lane redundant) ----
        float mx = -3.0e38f;
        #pragma unroll
        for (int mm = 0; mm < 16; ++mm) mx = fmaxf(mx, s_w2[mm][tl]);
        float ss = 0.f;
        #pragma unroll
        for (int mm = 0; mm < 16; ++mm) ss += __expf(s_w2[mm][tl] - mx);
        s_wn[k][tl] = __fdividef(__expf(w2v - mx), ss);
        __syncthreads();                                   // B2

        // ---- phase 4 ----
        if (t < 128) {
            const int c = t, mc = t & 15;
            float o = 0.f;
            #pragma unroll
            for (int kk = 0; kk < 16; ++kk) o += s_val[j][kk][c] * s_wn[kk][mc];
            out[(size_t)i * CCH + c] = o;
        }
    }
}

// ---------------------------------------------------------------------------
extern "C" void kernel_launch(void* const* d_in, const int* in_sizes, int n_in,
                              void* d_out, int out_size, void* d_ws, size_t ws_size,
                              hipStream_t stream) {
    (void)in_sizes; (void)n_in; (void)out_size; (void)ws_size;
    const float* p   = (const float*)d_in[0];
    const float* x   = (const float*)d_in[1];
    const float* Wq  = (const float*)d_in[2];
    const float* bq  = (const float*)d_in[3];
    const float* Wk  = (const float*)d_in[4];
    const float* bk  = (const float*)d_in[5];
    const float* Wv  = (const float*)d_in[6];
    const float* bv  = (const float*)d_in[7];
    const float* Wp1 = (const float*)d_in[8];
    const float* bp1 = (const float*)d_in[9];
    const float* g1  = (const float*)d_in[10];
    const float* be1 = (const float*)d_in[11];
    const float* Wp2 = (const float*)d_in[12];
    const float* bp2 = (const float*)d_in[13];
    const float* g2  = (const float*)d_in[14];
    const float* be2 = (const float*)d_in[15];
    const float* Ww1 = (const float*)d_in[16];
    const float* bw1 = (const float*)d_in[17];
    const float* g3  = (const float*)d_in[18];
    const float* be3 = (const float*)d_in[19];
    const float* Ww2 = (const float*)d_in[20];
    const float* bw2 = (const float*)d_in[21];
    float* out = (float*)d_out;

    // workspace layout
    char* ws = (char*)d_ws;
    int*    idxb  = (int*)ws;                                   // 512 KB
    float*  d2b   = (float*)(ws + (size_t)512 * 1024);          // 512 KB
    float*  xqb   = (float*)(ws + (size_t)1 * 1024 * 1024);     // 4 MB
    u16*    xkb16 = (u16*)(ws + (size_t)5 * 1024 * 1024);       // 2 MB
    u16*    xvb16 = (u16*)(ws + (size_t)7 * 1024 * 1024);       // 2 MB
    float4* c4b   = (float4*)(ws + (size_t)9 * 1024 * 1024);    // 128 KB

    pack_kernel<<<dim3(NPTS / 256), dim3(256), 0, stream>>>(p, c4b);
    knn_kernel<<<dim3(NPTS / (4 * QW)), dim3(256), 0, stream>>>(c4b, idxb, d2b);
    gemm3_kernel<<<dim3(NPTS / 64, CCH / 64, 3), dim3(256), 0, stream>>>(
        x, Wq, bq, Wk, bk, Wv, bv, xqb, xkb16, xvb16);
    fused_kernel<<<dim3(NPTS / PPB), dim3(256), 0, stream>>>(
        p, xqb, xkb16, xvb16, idxb, d2b,
        Wp1, bp1, g1, be1, Wp2, bp2, g2, be2, Ww1, bw1, g3, be3, Ww2, bw2, out);
}

// Round 13
// 104.976 us; speedup vs baseline: 1.0462x; 1.0462x over previous
//
#include <hip/hip_runtime.h>
#include <math.h>

// Problem constants (fixed-shape problem)
#define NPTS 8192
#define CCH  128
#define KNN  16
#define BN_RS 0.9999950000374997f   // 1/sqrt(1 + 1e-5)

typedef unsigned long long u64;
typedef unsigned short u16;

__device__ __forceinline__ u16 f2bf(float f) {   // round-to-nearest-even
    unsigned u = __float_as_uint(f);
    u += 0x7FFFu + ((u >> 16) & 1u);
    return (u16)(u >> 16);
}

__device__ __forceinline__ void bf8_to_f(const uint4 u, float* f) {
    f[0] = __uint_as_float(u.x << 16); f[1] = __uint_as_float(u.x & 0xffff0000u);
    f[2] = __uint_as_float(u.y << 16); f[3] = __uint_as_float(u.y & 0xffff0000u);
    f[4] = __uint_as_float(u.z << 16); f[5] = __uint_as_float(u.z & 0xffff0000u);
    f[6] = __uint_as_float(u.w << 16); f[7] = __uint_as_float(u.w & 0xffff0000u);
}

// ---------------------------------------------------------------------------
// Kernel P: pack candidate points as float4 (x, y, z, |p|^2)
// ---------------------------------------------------------------------------
__global__ __launch_bounds__(256) void pack_kernel(const float* __restrict__ p,
                                                   float4* __restrict__ c4) {
    const int j = blockIdx.x * 256 + threadIdx.x;
    if (j < NPTS) {
        const float x = p[3 * j + 0], y = p[3 * j + 1], z = p[3 * j + 2];
        c4[j] = make_float4(x, y, z, x * x + y * y + z * z);
    }
}

// ---------------------------------------------------------------------------
// Kernel A: KNN via sampled-threshold 1.25-pass select (R12 version — phase A
// reads candidates from block-shared LDS tiles; kept, measured ~2 us win).
// ---------------------------------------------------------------------------
#define QW    2
#define CAP   104
#define TILE  1024
#define SAMPN 4096

__device__ __forceinline__ u64 bitonic64(u64 v, const int lane) {
    #pragma unroll
    for (int k = 2; k <= 64; k <<= 1) {
        #pragma unroll
        for (int j = k >> 1; j > 0; j >>= 1) {
            const u64  o       = __shfl_xor(v, j);
            const bool takemin = (((lane & j) == 0) == ((lane & k) == 0));
            v = ((o < v) == takemin) ? o : v;
        }
    }
    return v;
}

__device__ __forceinline__ float bitonicf(float v, const int lane) {
    #pragma unroll
    for (int k = 2; k <= 64; k <<= 1) {
        #pragma unroll
        for (int j = k >> 1; j > 0; j >>= 1) {
            const float o      = __shfl_xor(v, j);
            const bool takemin = (((lane & j) == 0) == ((lane & k) == 0));
            v = ((o < v) == takemin) ? o : v;
        }
    }
    return v;
}

__device__ __forceinline__ float make_d2(const float4 c, const float m2x, const float m2y,
                                         const float m2z, const float qb) {
    float d2 = fmaf(m2x, c.x, fmaf(m2y, c.y, fmaf(m2z, c.z, c.w + qb)));
    return fmaxf(d2, 0.0f);
}

__global__ __launch_bounds__(256) void knn_kernel(const float4* __restrict__ c4,
                                                  int* __restrict__ oidx,
                                                  float* __restrict__ od2) {
    __shared__ float4 s_pt[TILE];            // 16 KB
    __shared__ u64    s_col[4][QW][CAP];     // 6.5 KB
    __shared__ int    s_cnt[4][QW];

    const int t     = threadIdx.x;
    const int wave  = t >> 6;
    const int lane  = t & 63;
    const int qbase = (blockIdx.x * 4 + wave) * QW;

    float m2x[QW], m2y[QW], m2z[QW], qb[QW];
    #pragma unroll
    for (int qi = 0; qi < QW; ++qi) {
        const float4 q = c4[qbase + qi];
        m2x[qi] = -2.0f * q.x;
        m2y[qi] = -2.0f * q.y;
        m2z[qi] = -2.0f * q.z;
        qb[qi]  = q.w;
    }
    if (lane < QW) s_cnt[wave][lane] = 0;   // synced by first staging barrier

    // ---- phase A: lane minima over first SAMPN candidates, LDS-tiled ----
    float bd[QW];
    #pragma unroll
    for (int qi = 0; qi < QW; ++qi) bd[qi] = 3.0e38f;

    for (int tb = 0; tb < SAMPN; tb += TILE) {
        __syncthreads();
        for (int jj = t; jj < TILE; jj += 256) s_pt[jj] = c4[tb + jj];
        __syncthreads();
        for (int l = lane; l < TILE; l += 128) {
            const float4 c0 = s_pt[l];
            const float4 c1 = s_pt[l + 64];
            #pragma unroll
            for (int qi = 0; qi < QW; ++qi) {
                const float d0 = make_d2(c0, m2x[qi], m2y[qi], m2z[qi], qb[qi]);
                const float d1 = make_d2(c1, m2x[qi], m2y[qi], m2z[qi], qb[qi]);
                bd[qi] = fminf(bd[qi], fminf(d0, d1));
            }
        }
    }

    float tauf[QW];
    #pragma unroll
    for (int qi = 0; qi < QW; ++qi) {
        const float s = bitonicf(bd[qi], lane);
        tauf[qi] = __shfl(s, 15);
    }

    // ---- phase B: collect pass over LDS tiles ----
    for (int tb = 0; tb < NPTS; tb += TILE) {
        __syncthreads();
        for (int jj = t; jj < TILE; jj += 256) s_pt[jj] = c4[tb + jj];
        __syncthreads();
        for (int l = lane; l < TILE; l += 128) {
            const float4 c0 = s_pt[l];
            const float4 c1 = s_pt[l + 64];
            const int j0 = tb + l, j1 = tb + l + 64;
            #pragma unroll
            for (int qi = 0; qi < QW; ++qi) {
                const float d0 = make_d2(c0, m2x[qi], m2y[qi], m2z[qi], qb[qi]);
                const float d1 = make_d2(c1, m2x[qi], m2y[qi], m2z[qi], qb[qi]);
                if (d0 <= tauf[qi]) {
                    const int pos = atomicAdd(&s_cnt[wave][qi], 1);
                    if (pos < CAP)
                        s_col[wave][qi][pos] = ((u64)__float_as_uint(d0) << 32) | (u64)(unsigned)j0;
                }
                if (d1 <= tauf[qi]) {
                    const int pos = atomicAdd(&s_cnt[wave][qi], 1);
                    if (pos < CAP)
                        s_col[wave][qi][pos] = ((u64)__float_as_uint(d1) << 32) | (u64)(unsigned)j1;
                }
            }
        }
    }

    // ---- final select per query ----
    #pragma unroll 1
    for (int qi = 0; qi < QW; ++qi) {
        const int q = qbase + qi;
        int M = s_cnt[wave][qi];

        if (M > CAP) {
            float fb = 3.0e38f;
            for (int l = lane; l < NPTS; l += 64)
                fb = fminf(fb, make_d2(c4[l], m2x[qi], m2y[qi], m2z[qi], qb[qi]));
            const float s    = bitonicf(fb, lane);
            const float tau2 = __shfl(s, 15);
            if (lane == 0) s_cnt[wave][qi] = 0;
            for (int l = lane; l < NPTS; l += 64) {
                const float d = make_d2(c4[l], m2x[qi], m2y[qi], m2z[qi], qb[qi]);
                if (d <= tau2) {
                    const int pos = atomicAdd(&s_cnt[wave][qi], 1);
                    if (pos < CAP)
                        s_col[wave][qi][pos] = ((u64)__float_as_uint(d) << 32) | (u64)(unsigned)l;
                }
            }
            M = s_cnt[wave][qi];
            if (M > CAP) M = CAP;
        }

        if (M <= 64) {
            u64 v = (lane < M) ? s_col[wave][qi][lane] : ~0ull;
            v = bitonic64(v, lane);
            if (lane < KNN) {
                oidx[q * KNN + lane] = (int)(v & 0xffffffffu);
                od2 [q * KNN + lane] = __uint_as_float((unsigned)(v >> 32));
            }
        } else {
            u64 a = (lane < M) ? s_col[wave][qi][lane] : ~0ull;
            a = bitonic64(a, lane);
            u64 b = (lane + 64 < M) ? s_col[wave][qi][lane + 64] : ~0ull;
            b = bitonic64(b, lane);
            const u64 bs = __shfl(b, lane & 15);
            u64 mv = (lane < 16) ? a : ((lane < 32) ? bs : ~0ull);
            mv = bitonic64(mv, lane);
            if (lane < KNN) {
                oidx[q * KNN + lane] = (int)(mv & 0xffffffffu);
                od2 [q * KNN + lane] = __uint_as_float((unsigned)(mv >> 32));
            }
        }
    }
}

// ---------------------------------------------------------------------------
// Kernel B: three fp32 GEMMs; xq fp32, xk/xv bf16.
// R13: A stored TRANSPOSED in LDS (AsT[k][r], pad 65) so the inner loop does
// 2 b128 LDS reads per k-iter (A read = 16-lane same-address broadcast; B
// read bank-spread) instead of 4 stride-68 scalar reads + 1 b128.  gemm3 was
// LDS-issue-bound (~20 us LDS-pipe vs 5 us FMA floor).  A-staging writes are
// bank(4lc+e+lr+16i)%32 = exactly 2-way aliased (free).
// ---------------------------------------------------------------------------
__global__ __launch_bounds__(256) void gemm3_kernel(
    const float* __restrict__ x,
    const float* __restrict__ Wq, const float* __restrict__ bq,
    const float* __restrict__ Wk, const float* __restrict__ bk,
    const float* __restrict__ Wv, const float* __restrict__ bv,
    float* __restrict__ xq, u16* __restrict__ xk16, u16* __restrict__ xv16) {
    const int which = blockIdx.z;
    const float* W    = (which == 0) ? Wq : (which == 1) ? Wk : Wv;
    const float* bias = (which == 0) ? bq : (which == 1) ? bk : bv;

    const int row0 = blockIdx.x * 64;
    const int col0 = blockIdx.y * 64;

    __shared__ float AsT[64][65];   // AsT[k][r] = x[row0+r][kk+k]
    __shared__ float Bs[64][68];

    const int t  = threadIdx.x;
    const int lr = t >> 4;
    const int lc = t & 15;
    const int or0 = (t >> 4) * 4;
    const int oc0 = (t & 15) * 4;

    float acc[4][4] = {};

    for (int kk = 0; kk < CCH; kk += 64) {
        __syncthreads();
        #pragma unroll
        for (int i = 0; i < 4; ++i) {
            const int r = lr + i * 16;
            const float4 av = *(const float4*)&x[(size_t)(row0 + r) * CCH + kk + lc * 4];
            AsT[lc * 4 + 0][r] = av.x;
            AsT[lc * 4 + 1][r] = av.y;
            AsT[lc * 4 + 2][r] = av.z;
            AsT[lc * 4 + 3][r] = av.w;
            *(float4*)&Bs[r][lc * 4] =
                *(const float4*)&W[(size_t)(kk + r) * CCH + col0 + lc * 4];
        }
        __syncthreads();
        #pragma unroll 8
        for (int k = 0; k < 64; ++k) {
            const float4 a = *(const float4*)&AsT[k][or0];   // broadcast within oc-group
            const float4 b = *(const float4*)&Bs[k][oc0];
            acc[0][0] += a.x * b.x; acc[0][1] += a.x * b.y; acc[0][2] += a.x * b.z; acc[0][3] += a.x * b.w;
            acc[1][0] += a.y * b.x; acc[1][1] += a.y * b.y; acc[1][2] += a.y * b.z; acc[1][3] += a.y * b.w;
            acc[2][0] += a.z * b.x; acc[2][1] += a.z * b.y; acc[2][2] += a.z * b.z; acc[2][3] += a.z * b.w;
            acc[3][0] += a.w * b.x; acc[3][1] += a.w * b.y; acc[3][2] += a.w * b.z; acc[3][3] += a.w * b.w;
        }
    }

    const float4 bb = *(const float4*)&bias[col0 + oc0];
    if (which == 0) {
        #pragma unroll
        for (int i = 0; i < 4; ++i) {
            const int r = row0 + or0 + i;
            float4 o;
            o.x = acc[i][0] + bb.x;
            o.y = acc[i][1] + bb.y;
            o.z = acc[i][2] + bb.z;
            o.w = acc[i][3] + bb.w;
            *(float4*)&xq[(size_t)r * CCH + col0 + oc0] = o;
        }
    } else {
        u16* o16 = (which == 1) ? xk16 : xv16;
        #pragma unroll
        for (int i = 0; i < 4; ++i) {
            const int r = row0 + or0 + i;
            ushort4 h;
            h.x = f2bf(acc[i][0] + bb.x);
            h.y = f2bf(acc[i][1] + bb.y);
            h.z = f2bf(acc[i][2] + bb.z);
            h.w = f2bf(acc[i][3] + bb.w);
            *(ushort4*)&o16[(size_t)r * CCH + col0 + oc0] = h;
        }
    }
}

// ---------------------------------------------------------------------------
// Kernel C: fused per-point attention, v7 (R11 version, verbatim — measured
// 44.6 us; PPB=2 variant regressed and is abandoned).
// ---------------------------------------------------------------------------
__global__ __launch_bounds__(256) void fused_kernel(
    const float* __restrict__ p,
    const float* __restrict__ xqg, const u16* __restrict__ xkg, const u16* __restrict__ xvg,
    const int* __restrict__ nidx, const float* __restrict__ nd2,
    const float* __restrict__ Wp1, const float* __restrict__ bp1,
    const float* __restrict__ g1,  const float* __restrict__ be1,
    const float* __restrict__ Wp2, const float* __restrict__ bp2,
    const float* __restrict__ g2,  const float* __restrict__ be2,
    const float* __restrict__ Ww1, const float* __restrict__ bw1,
    const float* __restrict__ g3,  const float* __restrict__ be3,
    const float* __restrict__ Ww2, const float* __restrict__ bw2,
    float* __restrict__ out) {
    const int i = blockIdx.x;
    const int t = threadIdx.x;

    __shared__ float s_w1tA[16][66];
    __shared__ float s_w1tB[16][66];
    __shared__ float s_val[16][132];
    __shared__ float s_w2[16][17];
    __shared__ float s_wn[16][17];

    const int k  = t >> 4;
    const int tl = t & 15;
    const int c0 = tl * 8;

    // ---- issue long-latency loads first ----
    const int   jn  = nidx[i * KNN + k];
    const float d2v = nd2[i * KNN + k];
    const uint4 ku = *(const uint4*)&xkg[(size_t)jn * CCH + c0];   // 8 bf16
    const uint4 vu = *(const uint4*)&xvg[(size_t)jn * CCH + c0];   // 8 bf16

    float ww2row[16];
    {
        const float4 r0 = *(const float4*)&Ww2[tl * 16 + 0];
        const float4 r1 = *(const float4*)&Ww2[tl * 16 + 4];
        const float4 r2 = *(const float4*)&Ww2[tl * 16 + 8];
        const float4 r3 = *(const float4*)&Ww2[tl * 16 + 12];
        ww2row[0]=r0.x; ww2row[1]=r0.y; ww2row[2]=r0.z; ww2row[3]=r0.w;
        ww2row[4]=r1.x; ww2row[5]=r1.y; ww2row[6]=r1.z; ww2row[7]=r1.w;
        ww2row[8]=r2.x; ww2row[9]=r2.y; ww2row[10]=r2.z; ww2row[11]=r2.w;
        ww2row[12]=r3.x; ww2row[13]=r3.y; ww2row[14]=r3.z; ww2row[15]=r3.w;
    }
    const float bw1m = bw1[tl];
    const float g3m  = g3[tl] * BN_RS;
    const float be3m = be3[tl];
    const float bw2m = bw2[tl];

    #pragma unroll
    for (int j = 0; j < 8; ++j) {
        const int e2   = t + j * 256;
        const int m    = e2 & 15;
        const int csrc = e2 >> 4;
        const int col  = ((csrc >> 3) << 2) | (csrc & 3);
        const float v  = Ww1[e2];
        if (csrc & 4) s_w1tB[m][col] = v;
        else          s_w1tA[m][col] = v;
    }

    const float dw  = __expf(-sqrtf(fmaxf(d2v, 0.f)));
    const float prx = p[jn * 3 + 0] - p[i * 3 + 0];
    const float pry = p[jn * 3 + 1] - p[i * 3 + 1];
    const float prz = p[jn * 3 + 2] - p[i * 3 + 2];
    float tt[3];
    #pragma unroll
    for (int e = 0; e < 3; ++e) {
        float v = prx * Wp1[0 * 3 + e] + pry * Wp1[1 * 3 + e] + prz * Wp1[2 * 3 + e] + bp1[e];
        v = v * (g1[e] * BN_RS) + be1[e];
        tt[e] = fmaxf(v, 0.f);
    }

    float xk8[8], xv8[8];
    bf8_to_f(ku, xk8);
    bf8_to_f(vu, xv8);

    float wv8[8];
    #pragma unroll
    for (int h = 0; h < 2; ++h) {
        const int cc = c0 + h * 4;
        const float4 w0  = *(const float4*)&Wp2[cc];
        const float4 w1  = *(const float4*)&Wp2[128 + cc];
        const float4 w2  = *(const float4*)&Wp2[256 + cc];
        const float4 bp  = *(const float4*)&bp2[cc];
        const float4 xq4 = *(const float4*)&xqg[(size_t)i * CCH + cc];
        const float4 gg  = *(const float4*)&g2[cc];
        const float4 bb  = *(const float4*)&be2[cc];
        float4 val4;
        {
            const float pr = tt[0] * w0.x + tt[1] * w1.x + tt[2] * w2.x + bp.x;
            wv8[h * 4 + 0] = fmaxf(((xq4.x - xk8[h * 4 + 0]) + pr) * (gg.x * BN_RS) + bb.x, 0.f);
            val4.x = xv8[h * 4 + 0] * dw + pr;
        }
        {
            const float pr = tt[0] * w0.y + tt[1] * w1.y + tt[2] * w2.y + bp.y;
            wv8[h * 4 + 1] = fmaxf(((xq4.y - xk8[h * 4 + 1]) + pr) * (gg.y * BN_RS) + bb.y, 0.f);
            val4.y = xv8[h * 4 + 1] * dw + pr;
        }
        {
            const float pr = tt[0] * w0.z + tt[1] * w1.z + tt[2] * w2.z + bp.z;
            wv8[h * 4 + 2] = fmaxf(((xq4.z - xk8[h * 4 + 2]) + pr) * (gg.z * BN_RS) + bb.z, 0.f);
            val4.z = xv8[h * 4 + 2] * dw + pr;
        }
        {
            const float pr = tt[0] * w0.w + tt[1] * w1.w + tt[2] * w2.w + bp.w;
            wv8[h * 4 + 3] = fmaxf(((xq4.w - xk8[h * 4 + 3]) + pr) * (gg.w * BN_RS) + bb.w, 0.f);
            val4.w = xv8[h * 4 + 3] * dw + pr;
        }
        *(float4*)&s_val[k][cc] = val4;
    }
    __syncthreads();                                   // B0

    float pp[16];
    #pragma unroll
    for (int m = 0; m < 16; ++m) {
        const float4 a = *(const float4*)&s_w1tA[m][tl * 4];
        const float4 b = *(const float4*)&s_w1tB[m][tl * 4];
        pp[m] = wv8[0] * a.x + wv8[1] * a.y + wv8[2] * a.z + wv8[3] * a.w
              + wv8[4] * b.x + wv8[5] * b.y + wv8[6] * b.z + wv8[7] * b.w;
    }
    {
        float q8[8];
        #pragma unroll
        for (int jj = 0; jj < 8; ++jj) {
            const float send = (tl & 8) ? pp[jj] : pp[jj + 8];
            const float keep = (tl & 8) ? pp[jj + 8] : pp[jj];
            q8[jj] = keep + __shfl_xor(send, 8);
        }
        float q4[4];
        #pragma unroll
        for (int jj = 0; jj < 4; ++jj) {
            const float send = (tl & 4) ? q8[jj] : q8[jj + 4];
            const float keep = (tl & 4) ? q8[jj + 4] : q8[jj];
            q4[jj] = keep + __shfl_xor(send, 4);
        }
        float q2[2];
        #pragma unroll
        for (int jj = 0; jj < 2; ++jj) {
            const float send = (tl & 2) ? q4[jj] : q4[jj + 2];
            const float keep = (tl & 2) ? q4[jj + 2] : q4[jj];
            q2[jj] = keep + __shfl_xor(send, 2);
        }
        const float s1 = (tl & 1) ? q2[0] : q2[1];
        const float k1 = (tl & 1) ? q2[1] : q2[0];
        pp[0] = k1 + __shfl_xor(s1, 1);        // w1[k][m=tl]
    }

    const float rr = fmaxf((pp[0] + bw1m) * g3m + be3m, 0.f);

    float p2[16];
    #pragma unroll
    for (int j2 = 0; j2 < 16; ++j2) p2[j2] = rr * ww2row[j2];
    float w2v;
    {
        float q8[8];
        #pragma unroll
        for (int jj = 0; jj < 8; ++jj) {
            const float send = (tl & 8) ? p2[jj] : p2[jj + 8];
            const float keep = (tl & 8) ? p2[jj + 8] : p2[jj];
            q8[jj] = keep + __shfl_xor(send, 8);
        }
        float q4[4];
        #pragma unroll
        for (int jj = 0; jj < 4; ++jj) {
            const float send = (tl & 4) ? q8[jj] : q8[jj + 4];
            const float keep = (tl & 4) ? q8[jj + 4] : q8[jj];
            q4[jj] = keep + __shfl_xor(send, 4);
        }
        float q2[2];
        #pragma unroll
        for (int jj = 0; jj < 2; ++jj) {
            const float send = (tl & 2) ? q4[jj] : q4[jj + 2];
            const float keep = (tl & 2) ? q4[jj + 2] : q4[jj];
            q2[jj] = keep + __shfl_xor(send, 2);
        }
        const float s1 = (tl & 1) ? q2[0] : q2[1];
        const float k1 = (tl & 1) ? q2[1] : q2[0];
        w2v = k1 + __shfl_xor(s1, 1) + bw2m;   // w2[k][m2=tl]
    }
    s_w2[k][tl] = w2v;
    __syncthreads();                                   // B1

    float mx = -3.0e38f;
    #pragma unroll
    for (int mm = 0; mm < 16; ++mm) mx = fmaxf(mx, s_w2[mm][tl]);
    float ss = 0.f;
    #pragma unroll
    for (int mm = 0; mm < 16; ++mm) ss += __expf(s_w2[mm][tl] - mx);
    s_wn[k][tl] = __fdividef(__expf(w2v - mx), ss);
    __syncthreads();                                   // B2

    if (t < 128) {
        const int c = t, mc = t & 15;
        float o = 0.f;
        #pragma unroll
        for (int kk = 0; kk < 16; ++kk) o += s_val[kk][c] * s_wn[kk][mc];
        out[(size_t)i * CCH + c] = o;
    }
}

// ---------------------------------------------------------------------------
extern "C" void kernel_launch(void* const* d_in, const int* in_sizes, int n_in,
                              void* d_out, int out_size, void* d_ws, size_t ws_size,
                              hipStream_t stream) {
    (void)in_sizes; (void)n_in; (void)out_size; (void)ws_size;
    const float* p   = (const float*)d_in[0];
    const float* x   = (const float*)d_in[1];
    const float* Wq  = (const float*)d_in[2];
    const float* bq  = (const float*)d_in[3];
    const float* Wk  = (const float*)d_in[4];
    const float* bk  = (const float*)d_in[5];
    const float* Wv  = (const float*)d_in[6];
    const float* bv  = (const float*)d_in[7];
    const float* Wp1 = (const float*)d_in[8];
    const float* bp1 = (const float*)d_in[9];
    const float* g1  = (const float*)d_in[10];
    const float* be1 = (const float*)d_in[11];
    const float* Wp2 = (const float*)d_in[12];
    const float* bp2 = (const float*)d_in[13];
    const float* g2  = (const float*)d_in[14];
    const float* be2 = (const float*)d_in[15];
    const float* Ww1 = (const float*)d_in[16];
    const float* bw1 = (const float*)d_in[17];
    const float* g3  = (const float*)d_in[18];
    const float* be3 = (const float*)d_in[19];
    const float* Ww2 = (const float*)d_in[20];
    const float* bw2 = (const float*)d_in[21];
    float* out = (float*)d_out;

    // workspace layout
    char* ws = (char*)d_ws;
    int*    idxb  = (int*)ws;                                   // 512 KB
    float*  d2b   = (float*)(ws + (size_t)512 * 1024);          // 512 KB
    float*  xqb   = (float*)(ws + (size_t)1 * 1024 * 1024);     // 4 MB
    u16*    xkb16 = (u16*)(ws + (size_t)5 * 1024 * 1024);       // 2 MB
    u16*    xvb16 = (u16*)(ws + (size_t)7 * 1024 * 1024);       // 2 MB
    float4* c4b   = (float4*)(ws + (size_t)9 * 1024 * 1024);    // 128 KB

    pack_kernel<<<dim3(NPTS / 256), dim3(256), 0, stream>>>(p, c4b);
    knn_kernel<<<dim3(NPTS / (4 * QW)), dim3(256), 0, stream>>>(c4b, idxb, d2b);
    gemm3_kernel<<<dim3(NPTS / 64, CCH / 64, 3), dim3(256), 0, stream>>>(
        x, Wq, bq, Wk, bk, Wv, bv, xqb, xkb16, xvb16);
    fused_kernel<<<dim3(NPTS), dim3(256), 0, stream>>>(
        p, xqb, xkb16, xvb16, idxb, d2b,
        Wp1, bp1, g1, be1, Wp2, bp2, g2, be2, Ww1, bw1, g3, be3, Ww2, bw2, out);
}

// Round 14
// 89.375 us; speedup vs baseline: 1.2288x; 1.1746x over previous
//
#include <hip/hip_runtime.h>
#include <math.h>

// Problem constants (fixed-shape problem)
#define NPTS 8192
#define CCH  128
#define KNN  16
#define BN_RS 0.9999950000374997f   // 1/sqrt(1 + 1e-5)

typedef unsigned long long u64;
typedef unsigned short u16;
typedef __attribute__((ext_vector_type(8))) short short8;
typedef __attribute__((ext_vector_type(4))) float f32x4;

__device__ __forceinline__ u16 f2bf(float f) {   // round-to-nearest-even
    unsigned u = __float_as_uint(f);
    u += 0x7FFFu + ((u >> 16) & 1u);
    return (u16)(u >> 16);
}

__device__ __forceinline__ void bf8_to_f(const uint4 u, float* f) {
    f[0] = __uint_as_float(u.x << 16); f[1] = __uint_as_float(u.x & 0xffff0000u);
    f[2] = __uint_as_float(u.y << 16); f[3] = __uint_as_float(u.y & 0xffff0000u);
    f[4] = __uint_as_float(u.z << 16); f[5] = __uint_as_float(u.z & 0xffff0000u);
    f[6] = __uint_as_float(u.w << 16); f[7] = __uint_as_float(u.w & 0xffff0000u);
}

// ---------------------------------------------------------------------------
// Kernel P: pack candidate points as float4 (x, y, z, |p|^2)
// ---------------------------------------------------------------------------
__global__ __launch_bounds__(256) void pack_kernel(const float* __restrict__ p,
                                                   float4* __restrict__ c4) {
    const int j = blockIdx.x * 256 + threadIdx.x;
    if (j < NPTS) {
        const float x = p[3 * j + 0], y = p[3 * j + 1], z = p[3 * j + 2];
        c4[j] = make_float4(x, y, z, x * x + y * y + z * z);
    }
}

// ---------------------------------------------------------------------------
// Kernel A: KNN via sampled-threshold 1.25-pass select (R12/R13 version).
// ---------------------------------------------------------------------------
#define QW    2
#define CAP   104
#define TILE  1024
#define SAMPN 4096

__device__ __forceinline__ u64 bitonic64(u64 v, const int lane) {
    #pragma unroll
    for (int k = 2; k <= 64; k <<= 1) {
        #pragma unroll
        for (int j = k >> 1; j > 0; j >>= 1) {
            const u64  o       = __shfl_xor(v, j);
            const bool takemin = (((lane & j) == 0) == ((lane & k) == 0));
            v = ((o < v) == takemin) ? o : v;
        }
    }
    return v;
}

__device__ __forceinline__ float bitonicf(float v, const int lane) {
    #pragma unroll
    for (int k = 2; k <= 64; k <<= 1) {
        #pragma unroll
        for (int j = k >> 1; j > 0; j >>= 1) {
            const float o      = __shfl_xor(v, j);
            const bool takemin = (((lane & j) == 0) == ((lane & k) == 0));
            v = ((o < v) == takemin) ? o : v;
        }
    }
    return v;
}

__device__ __forceinline__ float make_d2(const float4 c, const float m2x, const float m2y,
                                         const float m2z, const float qb) {
    float d2 = fmaf(m2x, c.x, fmaf(m2y, c.y, fmaf(m2z, c.z, c.w + qb)));
    return fmaxf(d2, 0.0f);
}

__global__ __launch_bounds__(256) void knn_kernel(const float4* __restrict__ c4,
                                                  int* __restrict__ oidx,
                                                  float* __restrict__ od2) {
    __shared__ float4 s_pt[TILE];            // 16 KB
    __shared__ u64    s_col[4][QW][CAP];     // 6.5 KB
    __shared__ int    s_cnt[4][QW];

    const int t     = threadIdx.x;
    const int wave  = t >> 6;
    const int lane  = t & 63;
    const int qbase = (blockIdx.x * 4 + wave) * QW;

    float m2x[QW], m2y[QW], m2z[QW], qb[QW];
    #pragma unroll
    for (int qi = 0; qi < QW; ++qi) {
        const float4 q = c4[qbase + qi];
        m2x[qi] = -2.0f * q.x;
        m2y[qi] = -2.0f * q.y;
        m2z[qi] = -2.0f * q.z;
        qb[qi]  = q.w;
    }
    if (lane < QW) s_cnt[wave][lane] = 0;   // synced by first staging barrier

    // ---- phase A: lane minima over first SAMPN candidates, LDS-tiled ----
    float bd[QW];
    #pragma unroll
    for (int qi = 0; qi < QW; ++qi) bd[qi] = 3.0e38f;

    for (int tb = 0; tb < SAMPN; tb += TILE) {
        __syncthreads();
        for (int jj = t; jj < TILE; jj += 256) s_pt[jj] = c4[tb + jj];
        __syncthreads();
        for (int l = lane; l < TILE; l += 128) {
            const float4 c0 = s_pt[l];
            const float4 c1 = s_pt[l + 64];
            #pragma unroll
            for (int qi = 0; qi < QW; ++qi) {
                const float d0 = make_d2(c0, m2x[qi], m2y[qi], m2z[qi], qb[qi]);
                const float d1 = make_d2(c1, m2x[qi], m2y[qi], m2z[qi], qb[qi]);
                bd[qi] = fminf(bd[qi], fminf(d0, d1));
            }
        }
    }

    float tauf[QW];
    #pragma unroll
    for (int qi = 0; qi < QW; ++qi) {
        const float s = bitonicf(bd[qi], lane);
        tauf[qi] = __shfl(s, 15);
    }

    // ---- phase B: collect pass over LDS tiles ----
    for (int tb = 0; tb < NPTS; tb += TILE) {
        __syncthreads();
        for (int jj = t; jj < TILE; jj += 256) s_pt[jj] = c4[tb + jj];
        __syncthreads();
        for (int l = lane; l < TILE; l += 128) {
            const float4 c0 = s_pt[l];
            const float4 c1 = s_pt[l + 64];
            const int j0 = tb + l, j1 = tb + l + 64;
            #pragma unroll
            for (int qi = 0; qi < QW; ++qi) {
                const float d0 = make_d2(c0, m2x[qi], m2y[qi], m2z[qi], qb[qi]);
                const float d1 = make_d2(c1, m2x[qi], m2y[qi], m2z[qi], qb[qi]);
                if (d0 <= tauf[qi]) {
                    const int pos = atomicAdd(&s_cnt[wave][qi], 1);
                    if (pos < CAP)
                        s_col[wave][qi][pos] = ((u64)__float_as_uint(d0) << 32) | (u64)(unsigned)j0;
                }
                if (d1 <= tauf[qi]) {
                    const int pos = atomicAdd(&s_cnt[wave][qi], 1);
                    if (pos < CAP)
                        s_col[wave][qi][pos] = ((u64)__float_as_uint(d1) << 32) | (u64)(unsigned)j1;
                }
            }
        }
    }

    // ---- final select per query ----
    #pragma unroll 1
    for (int qi = 0; qi < QW; ++qi) {
        const int q = qbase + qi;
        int M = s_cnt[wave][qi];

        if (M > CAP) {
            float fb = 3.0e38f;
            for (int l = lane; l < NPTS; l += 64)
                fb = fminf(fb, make_d2(c4[l], m2x[qi], m2y[qi], m2z[qi], qb[qi]));
            const float s    = bitonicf(fb, lane);
            const float tau2 = __shfl(s, 15);
            if (lane == 0) s_cnt[wave][qi] = 0;
            for (int l = lane; l < NPTS; l += 64) {
                const float d = make_d2(c4[l], m2x[qi], m2y[qi], m2z[qi], qb[qi]);
                if (d <= tau2) {
                    const int pos = atomicAdd(&s_cnt[wave][qi], 1);
                    if (pos < CAP)
                        s_col[wave][qi][pos] = ((u64)__float_as_uint(d) << 32) | (u64)(unsigned)l;
                }
            }
            M = s_cnt[wave][qi];
            if (M > CAP) M = CAP;
        }

        if (M <= 64) {
            u64 v = (lane < M) ? s_col[wave][qi][lane] : ~0ull;
            v = bitonic64(v, lane);
            if (lane < KNN) {
                oidx[q * KNN + lane] = (int)(v & 0xffffffffu);
                od2 [q * KNN + lane] = __uint_as_float((unsigned)(v >> 32));
            }
        } else {
            u64 a = (lane < M) ? s_col[wave][qi][lane] : ~0ull;
            a = bitonic64(a, lane);
            u64 b = (lane + 64 < M) ? s_col[wave][qi][lane + 64] : ~0ull;
            b = bitonic64(b, lane);
            const u64 bs = __shfl(b, lane & 15);
            u64 mv = (lane < 16) ? a : ((lane < 32) ? bs : ~0ull);
            mv = bitonic64(mv, lane);
            if (lane < KNN) {
                oidx[q * KNN + lane] = (int)(mv & 0xffffffffu);
                od2 [q * KNN + lane] = __uint_as_float((unsigned)(mv >> 32));
            }
        }
    }
}

// ---------------------------------------------------------------------------
// Kernel B: three fp32 GEMMs; xq fp32, xk/xv bf16 (R13 AsT version).
// ---------------------------------------------------------------------------
__global__ __launch_bounds__(256) void gemm3_kernel(
    const float* __restrict__ x,
    const float* __restrict__ Wq, const float* __restrict__ bq,
    const float* __restrict__ Wk, const float* __restrict__ bk,
    const float* __restrict__ Wv, const float* __restrict__ bv,
    float* __restrict__ xq, u16* __restrict__ xk16, u16* __restrict__ xv16) {
    const int which = blockIdx.z;
    const float* W    = (which == 0) ? Wq : (which == 1) ? Wk : Wv;
    const float* bias = (which == 0) ? bq : (which == 1) ? bk : bv;

    const int row0 = blockIdx.x * 64;
    const int col0 = blockIdx.y * 64;

    __shared__ float AsT[64][65];   // AsT[k][r] = x[row0+r][kk+k]
    __shared__ float Bs[64][68];

    const int t  = threadIdx.x;
    const int lr = t >> 4;
    const int lc = t & 15;
    const int or0 = (t >> 4) * 4;
    const int oc0 = (t & 15) * 4;

    float acc[4][4] = {};

    for (int kk = 0; kk < CCH; kk += 64) {
        __syncthreads();
        #pragma unroll
        for (int i = 0; i < 4; ++i) {
            const int r = lr + i * 16;
            const float4 av = *(const float4*)&x[(size_t)(row0 + r) * CCH + kk + lc * 4];
            AsT[lc * 4 + 0][r] = av.x;
            AsT[lc * 4 + 1][r] = av.y;
            AsT[lc * 4 + 2][r] = av.z;
            AsT[lc * 4 + 3][r] = av.w;
            *(float4*)&Bs[r][lc * 4] =
                *(const float4*)&W[(size_t)(kk + r) * CCH + col0 + lc * 4];
        }
        __syncthreads();
        #pragma unroll 8
        for (int k = 0; k < 64; ++k) {
            const float4 a = *(const float4*)&AsT[k][or0];   // broadcast within oc-group
            const float4 b = *(const float4*)&Bs[k][oc0];
            acc[0][0] += a.x * b.x; acc[0][1] += a.x * b.y; acc[0][2] += a.x * b.z; acc[0][3] += a.x * b.w;
            acc[1][0] += a.y * b.x; acc[1][1] += a.y * b.y; acc[1][2] += a.y * b.z; acc[1][3] += a.y * b.w;
            acc[2][0] += a.z * b.x; acc[2][1] += a.z * b.y; acc[2][2] += a.z * b.z; acc[2][3] += a.z * b.w;
            acc[3][0] += a.w * b.x; acc[3][1] += a.w * b.y; acc[3][2] += a.w * b.z; acc[3][3] += a.w * b.w;
        }
    }

    const float4 bb = *(const float4*)&bias[col0 + oc0];
    if (which == 0) {
        #pragma unroll
        for (int i = 0; i < 4; ++i) {
            const int r = row0 + or0 + i;
            float4 o;
            o.x = acc[i][0] + bb.x;
            o.y = acc[i][1] + bb.y;
            o.z = acc[i][2] + bb.z;
            o.w = acc[i][3] + bb.w;
            *(float4*)&xq[(size_t)r * CCH + col0 + oc0] = o;
        }
    } else {
        u16* o16 = (which == 1) ? xk16 : xv16;
        #pragma unroll
        for (int i = 0; i < 4; ++i) {
            const int r = row0 + or0 + i;
            ushort4 h;
            h.x = f2bf(acc[i][0] + bb.x);
            h.y = f2bf(acc[i][1] + bb.y);
            h.z = f2bf(acc[i][2] + bb.z);
            h.w = f2bf(acc[i][3] + bb.w);
            *(ushort4*)&o16[(size_t)r * CCH + col0 + oc0] = h;
        }
    }
}

// ---------------------------------------------------------------------------
// Kernel C: fused per-point attention, v9 = v7 with the w-MLP done by MFMA.
//  - Phase 1 (all 256 thr): as v7, plus wv -> bf16 -> s_wv (XOR-swizzled
//    byte ^= (row&7)<<4, G4) so the MFMA A-frag read is ~2-way bank aliased.
//  - Ww1 staged once as bf16 s_w1t[m][c] (B-frag friendly, same swizzle).
//  - After B0, WAVE 0 ONLY: w1 = wv@Ww1 via 4x mfma_f32_16x16x32_bf16
//    (C-layout: row=(l>>4)*4+r = neighbor, col=l&15 = m — m89/m91-verified);
//    bn/relu; rr transposed through a 512B in-wave LDS scratch (DS ops are
//    in-order within a wave — no barrier); w2 = rr@Ww2 as one zero-padded
//    K=32 MFMA; softmax over neighbors via own-4 + xor16/xor32 shuffles;
//    write s_wn.  Waves 1-3 pass straight to B1 (their issue slots feed the
//    7 other resident blocks).
//  - Barriers: 2 (was 3).  Butterflies and pp-loop gone (~270 ops/thread).
// ---------------------------------------------------------------------------
__global__ __launch_bounds__(256) void fused_kernel(
    const float* __restrict__ p,
    const float* __restrict__ xqg, const u16* __restrict__ xkg, const u16* __restrict__ xvg,
    const int* __restrict__ nidx, const float* __restrict__ nd2,
    const float* __restrict__ Wp1, const float* __restrict__ bp1,
    const float* __restrict__ g1,  const float* __restrict__ be1,
    const float* __restrict__ Wp2, const float* __restrict__ bp2,
    const float* __restrict__ g2,  const float* __restrict__ be2,
    const float* __restrict__ Ww1, const float* __restrict__ bw1,
    const float* __restrict__ g3,  const float* __restrict__ be3,
    const float* __restrict__ Ww2, const float* __restrict__ bw2,
    float* __restrict__ out) {
    const int i = blockIdx.x;
    const int t = threadIdx.x;

    __shared__ __align__(16) u16 s_wv[2048];    // [16 nbr][128 ch] bf16, swizzled
    __shared__ __align__(16) u16 s_w1t[2048];   // [16 m][128 ch]  bf16, swizzled
    __shared__ __align__(16) u16 s_rr[256];     // [16 nbr][16 m]  bf16, plain
    __shared__ float s_val[16][132];
    __shared__ float s_wn[16][17];

    const int k  = t >> 4;      // neighbor 0..15
    const int tl = t & 15;      // channel-group
    const int c0 = tl * 8;

    // ---- issue long-latency gathers first ----
    const int   jn  = nidx[i * KNN + k];
    const float d2v = nd2[i * KNN + k];
    const uint4 ku = *(const uint4*)&xkg[(size_t)jn * CCH + c0];   // 8 bf16
    const uint4 vu = *(const uint4*)&xvg[(size_t)jn * CCH + c0];   // 8 bf16

    // ---- stage Ww1 as bf16, layout s_w1t[m][c] with row-XOR swizzle ----
    #pragma unroll
    for (int j = 0; j < 8; ++j) {
        const int e2 = t + j * 256;          // = c*16 + m
        const int m  = e2 & 15, c = e2 >> 4;
        const u16 hv = f2bf(Ww1[e2]);
        const int byte = m * 256 + ((c * 2) ^ ((m & 7) << 4));
        *(u16*)((char*)s_w1t + byte) = hv;
    }

    // ---- phase 1: pr + wv (regs) + val (LDS) ----
    const float dw  = __expf(-sqrtf(fmaxf(d2v, 0.f)));
    const float prx = p[jn * 3 + 0] - p[i * 3 + 0];
    const float pry = p[jn * 3 + 1] - p[i * 3 + 1];
    const float prz = p[jn * 3 + 2] - p[i * 3 + 2];
    float tt[3];
    #pragma unroll
    for (int e = 0; e < 3; ++e) {
        float v = prx * Wp1[0 * 3 + e] + pry * Wp1[1 * 3 + e] + prz * Wp1[2 * 3 + e] + bp1[e];
        v = v * (g1[e] * BN_RS) + be1[e];
        tt[e] = fmaxf(v, 0.f);
    }

    float xk8[8], xv8[8];
    bf8_to_f(ku, xk8);
    bf8_to_f(vu, xv8);

    float wv8[8];
    #pragma unroll
    for (int h = 0; h < 2; ++h) {
        const int cc = c0 + h * 4;
        const float4 w0  = *(const float4*)&Wp2[cc];
        const float4 w1  = *(const float4*)&Wp2[128 + cc];
        const float4 w2  = *(const float4*)&Wp2[256 + cc];
        const float4 bp  = *(const float4*)&bp2[cc];
        const float4 xq4 = *(const float4*)&xqg[(size_t)i * CCH + cc];
        const float4 gg  = *(const float4*)&g2[cc];
        const float4 bb  = *(const float4*)&be2[cc];
        float4 val4;
        {
            const float pr = tt[0] * w0.x + tt[1] * w1.x + tt[2] * w2.x + bp.x;
            wv8[h * 4 + 0] = fmaxf(((xq4.x - xk8[h * 4 + 0]) + pr) * (gg.x * BN_RS) + bb.x, 0.f);
            val4.x = xv8[h * 4 + 0] * dw + pr;
        }
        {
            const float pr = tt[0] * w0.y + tt[1] * w1.y + tt[2] * w2.y + bp.y;
            wv8[h * 4 + 1] = fmaxf(((xq4.y - xk8[h * 4 + 1]) + pr) * (gg.y * BN_RS) + bb.y, 0.f);
            val4.y = xv8[h * 4 + 1] * dw + pr;
        }
        {
            const float pr = tt[0] * w0.z + tt[1] * w1.z + tt[2] * w2.z + bp.z;
            wv8[h * 4 + 2] = fmaxf(((xq4.z - xk8[h * 4 + 2]) + pr) * (gg.z * BN_RS) + bb.z, 0.f);
            val4.z = xv8[h * 4 + 2] * dw + pr;
        }
        {
            const float pr = tt[0] * w0.w + tt[1] * w1.w + tt[2] * w2.w + bp.w;
            wv8[h * 4 + 3] = fmaxf(((xq4.w - xk8[h * 4 + 3]) + pr) * (gg.w * BN_RS) + bb.w, 0.f);
            val4.w = xv8[h * 4 + 3] * dw + pr;
        }
        *(float4*)&s_val[k][cc] = val4;
    }

    // wv -> bf16 -> s_wv[k][c0..c0+7], swizzled, one b128 write
    {
        uint4 wp;
        wp.x = (unsigned)f2bf(wv8[0]) | ((unsigned)f2bf(wv8[1]) << 16);
        wp.y = (unsigned)f2bf(wv8[2]) | ((unsigned)f2bf(wv8[3]) << 16);
        wp.z = (unsigned)f2bf(wv8[4]) | ((unsigned)f2bf(wv8[5]) << 16);
        wp.w = (unsigned)f2bf(wv8[6]) | ((unsigned)f2bf(wv8[7]) << 16);
        const int byte = k * 256 + ((c0 * 2) ^ ((k & 7) << 4));
        *(uint4*)((char*)s_wv + byte) = wp;
    }
    __syncthreads();                                   // B0

    // ---- wave 0 only: MFMA w-MLP + softmax ----
    if (t < 64) {
        const int l  = t;
        const int lr = l & 15;      // A row / B col
        const int lg = l >> 4;      // k-chunk group

        // w1 = wv(16x128) @ Ww1(128x16), 4 chunks of K=32
        f32x4 acc = {0.f, 0.f, 0.f, 0.f};
        #pragma unroll
        for (int c = 0; c < 4; ++c) {
            const int off = ((lg * 16 + 64 * c) ^ ((lr & 7) << 4));
            const short8 a = *(const short8*)((const char*)s_wv  + lr * 256 + off);
            const short8 b = *(const short8*)((const char*)s_w1t + lr * 256 + off);
            acc = __builtin_amdgcn_mfma_f32_16x16x32_bf16(a, b, acc, 0, 0, 0);
        }
        // C-layout: lane holds w1[row = lg*4+r (neighbor)][col = lr (m)]
        const float bw1m = bw1[lr];
        const float g3m  = g3[lr] * BN_RS;
        const float be3m = be3[lr];
        #pragma unroll
        for (int r = 0; r < 4; ++r) {
            const float rr = fmaxf((acc[r] + bw1m) * g3m + be3m, 0.f);
            *(u16*)((char*)s_rr + (lg * 4 + r) * 32 + lr * 2) = f2bf(rr);
        }
        // DS ops are in-order within a wave: reads below see the writes above.

        // w2 = rr(16x16) @ Ww2(16x16) as one zero-padded K=32 MFMA
        short8 a2 = (short8){0, 0, 0, 0, 0, 0, 0, 0};
        short8 b2 = (short8){0, 0, 0, 0, 0, 0, 0, 0};
        if (lg < 2) {
            a2 = *(const short8*)((const char*)s_rr + lr * 32 + lg * 16);
            #pragma unroll
            for (int e = 0; e < 8; ++e)
                b2[e] = (short)f2bf(Ww2[(lg * 8 + e) * 16 + lr]);
        }
        f32x4 acc2 = {0.f, 0.f, 0.f, 0.f};
        acc2 = __builtin_amdgcn_mfma_f32_16x16x32_bf16(a2, b2, acc2, 0, 0, 0);

        // lane holds w2[neighbor = lg*4+r][m2 = lr] (+bw2)
        const float bw2m = bw2[lr];
        float w2v[4];
        #pragma unroll
        for (int r = 0; r < 4; ++r) w2v[r] = acc2[r] + bw2m;

        // softmax over the 16 neighbors (column lr): own-4 + xor16 + xor32
        float mx = fmaxf(fmaxf(w2v[0], w2v[1]), fmaxf(w2v[2], w2v[3]));
        mx = fmaxf(mx, __shfl_xor(mx, 16));
        mx = fmaxf(mx, __shfl_xor(mx, 32));
        float ev[4], ss = 0.f;
        #pragma unroll
        for (int r = 0; r < 4; ++r) { ev[r] = __expf(w2v[r] - mx); ss += ev[r]; }
        ss += __shfl_xor(ss, 16);
        ss += __shfl_xor(ss, 32);
        const float inv = __fdividef(1.f, ss);
        #pragma unroll
        for (int r = 0; r < 4; ++r) s_wn[lg * 4 + r][lr] = ev[r] * inv;
    }
    __syncthreads();                                   // B1

    // ---- phase 4: out[c] = sum_k val[k][c] * wn[k][c & 15] ----
    if (t < 128) {
        const int c = t, mc = t & 15;
        float o = 0.f;
        #pragma unroll
        for (int kk = 0; kk < 16; ++kk) o += s_val[kk][c] * s_wn[kk][mc];
        out[(size_t)i * CCH + c] = o;
    }
}

// ---------------------------------------------------------------------------
extern "C" void kernel_launch(void* const* d_in, const int* in_sizes, int n_in,
                              void* d_out, int out_size, void* d_ws, size_t ws_size,
                              hipStream_t stream) {
    (void)in_sizes; (void)n_in; (void)out_size; (void)ws_size;
    const float* p   = (const float*)d_in[0];
    const float* x   = (const float*)d_in[1];
    const float* Wq  = (const float*)d_in[2];
    const float* bq  = (const float*)d_in[3];
    const float* Wk  = (const float*)d_in[4];
    const float* bk  = (const float*)d_in[5];
    const float* Wv  = (const float*)d_in[6];
    const float* bv  = (const float*)d_in[7];
    const float* Wp1 = (const float*)d_in[8];
    const float* bp1 = (const float*)d_in[9];
    const float* g1  = (const float*)d_in[10];
    const float* be1 = (const float*)d_in[11];
    const float* Wp2 = (const float*)d_in[12];
    const float* bp2 = (const float*)d_in[13];
    const float* g2  = (const float*)d_in[14];
    const float* be2 = (const float*)d_in[15];
    const float* Ww1 = (const float*)d_in[16];
    const float* bw1 = (const float*)d_in[17];
    const float* g3  = (const float*)d_in[18];
    const float* be3 = (const float*)d_in[19];
    const float* Ww2 = (const float*)d_in[20];
    const float* bw2 = (const float*)d_in[21];
    float* out = (float*)d_out;

    // workspace layout
    char* ws = (char*)d_ws;
    int*    idxb  = (int*)ws;                                   // 512 KB
    float*  d2b   = (float*)(ws + (size_t)512 * 1024);          // 512 KB
    float*  xqb   = (float*)(ws + (size_t)1 * 1024 * 1024);     // 4 MB
    u16*    xkb16 = (u16*)(ws + (size_t)5 * 1024 * 1024);       // 2 MB
    u16*    xvb16 = (u16*)(ws + (size_t)7 * 1024 * 1024);       // 2 MB
    float4* c4b   = (float4*)(ws + (size_t)9 * 1024 * 1024);    // 128 KB

    pack_kernel<<<dim3(NPTS / 256), dim3(256), 0, stream>>>(p, c4b);
    knn_kernel<<<dim3(NPTS / (4 * QW)), dim3(256), 0, stream>>>(c4b, idxb, d2b);
    gemm3_kernel<<<dim3(NPTS / 64, CCH / 64, 3), dim3(256), 0, stream>>>(
        x, Wq, bq, Wk, bk, Wv, bv, xqb, xkb16, xvb16);
    fused_kernel<<<dim3(NPTS), dim3(256), 0, stream>>>(
        p, xqb, xkb16, xvb16, idxb, d2b,
        Wp1, bp1, g1, be1, Wp2, bp2, g2, be2, Ww1, bw1, g3, be3, Ww2, bw2, out);
}